// Round 10
// baseline (232.748 us; speedup 1.0000x reference)
//
#include <hip/hip_runtime.h>
#include <hip/hip_bf16.h>
#include <math.h>

#define HID 1024
#define INTER 8192
#define TT 4096  // tokens = B*S

typedef __bf16 bf16x8 __attribute__((ext_vector_type(8)));
typedef float f32x4 __attribute__((ext_vector_type(4)));

__device__ __forceinline__ void gll16(const void* g, void* l) {
    __builtin_amdgcn_global_load_lds(
        (const __attribute__((address_space(1))) void*)g,
        (__attribute__((address_space(3))) void*)l, 16, 0, 0);
}

// inline-asm LDS read with immediate offset: invisible to SIInsertWaitcnts;
// RAW ordering is ours (counted lgkmcnt/vmcnt + sched_barrier pins).
template <int OFF>
__device__ __forceinline__ bf16x8 ds_read128o(unsigned addr) {
    bf16x8 r;
    asm volatile("ds_read_b128 %0, %1 offset:%c2" : "=v"(r) : "v"(addr), "i"(OFF));
    return r;
}

// cast x -> bf16, compute per-token scale s[t] = ew[t,0]+ew[t,1]
__global__ void k_prep(const float* __restrict__ x, const float* __restrict__ ew,
                       __hip_bfloat16* __restrict__ xb, float* __restrict__ s,
                       int n4, int T) {
    int stride = gridDim.x * blockDim.x;
    for (int i = blockIdx.x * blockDim.x + threadIdx.x; i < n4; i += stride) {
        float4 v = ((const float4*)x)[i];
        __hip_bfloat16* o = xb + (size_t)i * 4;
        o[0] = __float2bfloat16(v.x);
        o[1] = __float2bfloat16(v.y);
        o[2] = __float2bfloat16(v.z);
        o[3] = __float2bfloat16(v.w);
    }
    for (int t = blockIdx.x * blockDim.x + threadIdx.x; t < T; t += stride)
        s[t] = ew[2 * t] + ew[2 * t + 1];
}

// transpose + cast: in f32 [R][C] -> out bf16 [C][R]
__global__ void k_tcast(const float* __restrict__ in, __hip_bfloat16* __restrict__ out,
                        int R, int C) {
    __shared__ float tile[32][33];
    const int tx = threadIdx.x & 31, ty = threadIdx.x >> 5;  // 32x8
    const int br = blockIdx.y * 32, bc = blockIdx.x * 32;
#pragma unroll
    for (int j = 0; j < 32; j += 8)
        tile[ty + j][tx] = in[(size_t)(br + ty + j) * C + bc + tx];
    __syncthreads();
#pragma unroll
    for (int j = 0; j < 32; j += 8)
        out[(size_t)(bc + ty + j) * R + br + tx] = __float2bfloat16(tile[tx][ty + j]);
}

// ---------------------------------------------------------------------------
// 128x128 tile, BK=32, 4 waves (2x2, wave-tile 64x64), TRIPLE-buffered LDS
// (48KB -> up to 3 blocks/CU). The fix vs rounds 1-9: stage tile i+2 while
// computing tile i, so the boundary vmcnt(4) waits only on tile i+1's chunks
// issued a FULL iteration earlier (~2-iter lead > HBM latency) -> staging
// DMA latency finally leaves the critical path. WAR-safe: buf((i+2)%3) ==
// buf((i-1)%3), whose readers drained (lgkm0) before iter i-1's barrier.
// Per-wave disjoint stage chunks (stager = reader's buffer region), XOR
// swizzle (2-bit granule, BK=32) on pre-swizzled source + swizzled read
// (rule #21), asm ds_read_b128 + counted lgkm gates + pins (rule #18),
// one barrier per K-tile.
// EPI=0: gelu -> bf16 hOut.  EPI=1: unsafeAtomicAdd(s[row]*acc) into fOut.
// ---------------------------------------------------------------------------
template <int EPI>
__global__ __launch_bounds__(256, 3) void k_g3(
    const __hip_bfloat16* __restrict__ A, const __hip_bfloat16* __restrict__ Bt,
    __hip_bfloat16* __restrict__ hOut, float* __restrict__ fOut,
    const float* __restrict__ s, int Kfull, int nt, int Nout) {
    __shared__ __hip_bfloat16 sA[3][128][32];  // 8KB per buf
    __shared__ __hip_bfloat16 sB[3][128][32];
    const int tid = threadIdx.x;
    const int lane = tid & 63, wid = tid >> 6;  // 4 waves
    const int wr = wid >> 1, wc = wid & 1;      // 2x2 wave grid; wave tile 64x64

    // XCD-bijective swizzle; nwg % 8 == 0 by construction.
    const int nwg = gridDim.x * gridDim.y;
    const int wg = blockIdx.y * gridDim.x + blockIdx.x;
    const int swz = (wg & 7) * (nwg >> 3) + (wg >> 3);
    const int brow = (swz / gridDim.x) * 128;
    const int bcol = (swz % gridDim.x) * 128;
    const size_t kbase = (size_t)blockIdx.z * ((size_t)nt * 32);

    // --- per-wave staging: wave stages A rows [wid*32,+32) and B rows
    // [wid*32,+32) (disjoint; own vmcnt ledger). chunk = 16 rows x 32 cols
    // = 1KB per gll16; lane -> row 16j+(lane>>2), granule (lane&3), source
    // granule pre-XOR'd by row&3 (= (lane>>2)&3).
    const int colsw = (((lane & 3) ^ ((lane >> 2) & 3)) << 3);  // elements
    const __hip_bfloat16* gA2 =
        A + (size_t)(brow + wid * 32 + (lane >> 2)) * Kfull + kbase + colsw;
    const __hip_bfloat16* gB2 =
        Bt + (size_t)(bcol + wid * 32 + (lane >> 2)) * Kfull + kbase + colsw;
    char* ldsA2 = (char*)&sA[0][0][0] + wid * 2048;
    char* ldsB2 = (char*)&sB[0][0][0] + wid * 2048;
    const size_t chunkStep = (size_t)16 * Kfull;

    // read-side swizzled LDS byte addresses; row = (lane&15)+16m, granule
    // g=(lane>>4) stored at slot g^(row&3) = g^(lane&3).
    const unsigned baseA = (unsigned)(uintptr_t)&sA[0][0][0];
    const unsigned baseB = (unsigned)(uintptr_t)&sB[0][0][0];
    const unsigned gsw = (((lane >> 4) ^ (lane & 3)) << 4);
    const unsigned rdA = baseA + wr * 4096 + (lane & 15) * 64 + gsw;
    const unsigned rdB = baseB + wc * 4096 + (lane & 15) * 64 + gsw;

    f32x4 acc[4][4] = {};
    bf16x8 aF[4], bF[4];

#define STAGE(bufoff, t)                                                       \
    do {                                                                       \
        gll16(gA2 + (size_t)(t) * 32, ldsA2 + (bufoff));                       \
        gll16(gA2 + chunkStep + (size_t)(t) * 32, ldsA2 + (bufoff) + 1024);    \
        gll16(gB2 + (size_t)(t) * 32, ldsB2 + (bufoff));                       \
        gll16(gB2 + chunkStep + (size_t)(t) * 32, ldsB2 + (bufoff) + 1024);    \
    } while (0)
#define PIN() __builtin_amdgcn_sched_barrier(0)
#define BAR()                              \
    do {                                   \
        PIN();                             \
        __builtin_amdgcn_s_barrier();      \
        PIN();                             \
    } while (0)
#define WAIT_LG2() __builtin_amdgcn_s_waitcnt(0xC27F)  // lgkmcnt(2)
#define WAIT_LG0() __builtin_amdgcn_s_waitcnt(0xC07F)  // lgkmcnt(0)
#define WAIT_VM4() __builtin_amdgcn_s_waitcnt(0x0F74)  // vmcnt(4)
#define WAIT_VM0() __builtin_amdgcn_s_waitcnt(0x0F70)  // vmcnt(0)

    // prologue: tiles 0,1 into bufs 0,1; wait tile0 (oldest 4), publish.
    STAGE(0u, 0);
    STAGE(8192u, 1);
    WAIT_VM4();
    BAR();

    unsigned co = 0u, c1 = 8192u, c2 = 16384u;  // rotating buf byte offsets
#pragma unroll 1
    for (int i = 0; i < nt; ++i) {
        const bool more = (i + 2 < nt);
        const unsigned aA = rdA + co, aB = rdB + co;

        // ---- issue reads, FIFO order: aF0-3, bF0-1 [first 6], bF2-3
        aF[0] = ds_read128o<0>(aA);
        aF[1] = ds_read128o<1024>(aA);
        aF[2] = ds_read128o<2048>(aA);
        aF[3] = ds_read128o<3072>(aA);
        bF[0] = ds_read128o<0>(aB);
        bF[1] = ds_read128o<1024>(aB);
        bF[2] = ds_read128o<2048>(aB);
        bF[3] = ds_read128o<3072>(aB);

        // ---- stage tile i+2 into the buffer freed at iter i-1
        if (more) STAGE(c2, i + 2);

        __builtin_amdgcn_s_setprio(1);
        // ---- cluster 1: m0-3 x n0-1 (needs first 6 reads -> lgkm<=2)
        WAIT_LG2();
        PIN();
#pragma unroll
        for (int m = 0; m < 4; ++m)
#pragma unroll
            for (int n = 0; n < 2; ++n)
                acc[m][n] = __builtin_amdgcn_mfma_f32_16x16x32_bf16(
                    aF[m], bF[n], acc[m][n], 0, 0, 0);
        PIN();
        // ---- cluster 2: m0-3 x n2-3 (all reads done)
        WAIT_LG0();
        PIN();
#pragma unroll
        for (int m = 0; m < 4; ++m)
#pragma unroll
            for (int n = 0; n < 2; ++n)
                acc[m][2 + n] = __builtin_amdgcn_mfma_f32_16x16x32_bf16(
                    aF[m], bF[2 + n], acc[m][2 + n], 0, 0, 0);
        __builtin_amdgcn_s_setprio(0);
        PIN();
        // ---- boundary: tile i+1's 4 chunks (issued a full iter ago) must
        // be in LDS; tile i+2's 4 stay in flight across the barrier.
        if (more)
            WAIT_VM4();
        else
            WAIT_VM0();
        BAR();
        const unsigned t = co;  // rotate buffers
        co = c1;
        c1 = c2;
        c2 = t;
    }

    // epilogue
    const int orow = brow + wr * 64 + ((lane >> 4) << 2);
    const int ocol = bcol + wc * 64 + (lane & 15);
#pragma unroll
    for (int m = 0; m < 4; ++m) {
#pragma unroll
        for (int j = 0; j < 4; ++j) {
            const int r = orow + m * 16 + j;
            const size_t ro = (size_t)r * Nout;
            if (EPI == 0) {
#pragma unroll
                for (int n = 0; n < 4; ++n) {
                    float v = acc[m][n][j];
                    float u = 1.5957691216057308f * (v + 0.044715f * v * v * v);
                    float g = v / (1.0f + __expf(-u));
                    hOut[ro + ocol + n * 16] = __float2bfloat16(g);
                }
            } else {
                const float sc = s[r];
#pragma unroll
                for (int n = 0; n < 4; ++n)
                    unsafeAtomicAdd(&fOut[ro + ocol + n * 16], sc * acc[m][n][j]);
            }
        }
    }
#undef STAGE
#undef PIN
#undef BAR
#undef WAIT_LG2
#undef WAIT_LG0
#undef WAIT_VM4
#undef WAIT_VM0
}

extern "C" void kernel_launch(void* const* d_in, const int* in_sizes, int n_in,
                              void* d_out, int out_size, void* d_ws, size_t ws_size,
                              hipStream_t stream) {
    const float* x = (const float*)d_in[0];
    // d_in[1] = scores (unused), d_in[3] = top_experts (unused)
    const float* ew = (const float*)d_in[2];
    const float* w1 = (const float*)d_in[4];
    const float* w2 = (const float*)d_in[5];
    float* out = (float*)d_out;

    char* ws = (char*)d_ws;
    float* s = (float*)ws;                                                    // 16 KB
    __hip_bfloat16* xb = (__hip_bfloat16*)(ws + 16384);                       // 8 MB
    __hip_bfloat16* w1t = (__hip_bfloat16*)(ws + 16384 + 8388608);            // 16 MB
    __hip_bfloat16* w2t = (__hip_bfloat16*)(ws + 16384 + 8388608 + 16777216); // 16 MB
    __hip_bfloat16* h = (__hip_bfloat16*)(ws + 16384 + 8388608 + 2 * 16777216); // 64 MB

    k_prep<<<1024, 256, 0, stream>>>(x, ew, xb, s, (TT * HID) / 4, TT);

    dim3 t1(INTER / 32, HID / 32);
    k_tcast<<<t1, 256, 0, stream>>>(w1, w1t, HID, INTER);
    dim3 t2(HID / 32, INTER / 32);
    k_tcast<<<t2, 256, 0, stream>>>(w2, w2t, INTER, HID);

    // GEMM1: [4096 x 1024] x [1024 x 8192] -> h (gelu, bf16)
    dim3 g1(INTER / 128, TT / 128, 1);  // 64 x 32 = 2048 blocks
    k_g3<0><<<g1, 256, 0, stream>>>(xb, w1t, h, nullptr, nullptr, HID, HID / 32, INTER);

    // GEMM2: [4096 x 8192] x [8192 x 1024] -> out (f32, split-K=4 atomic combine)
    hipMemsetAsync(out, 0, (size_t)TT * HID * sizeof(float), stream);
    dim3 g2(HID / 128, TT / 128, 4);  // 8 x 32 x 4 = 1024 blocks
    k_g3<1><<<g2, 256, 0, stream>>>(h, w2t, nullptr, out, s, INTER, 2048 / 32, HID);
}